// Round 7
// baseline (476.607 us; speedup 1.0000x reference)
//
#include <hip/hip_runtime.h>
#include <hip/hip_bf16.h>
#include <stdint.h>

typedef __bf16 bf16_t;
typedef bf16_t bf16x8 __attribute__((ext_vector_type(8)));
typedef bf16_t bf16x4 __attribute__((ext_vector_type(4)));
typedef float f32x4 __attribute__((ext_vector_type(4)));

#define NN 10000
#define EE 80000
#define DD 1024
#define LL 2
#define MPAD 10112   /* 79*128 */
#define NEGS 0.2f

#define GLOAD_LDS16(g, l) \
    __builtin_amdgcn_global_load_lds((__attribute__((address_space(1))) void*)(void*)(g), \
                                     (__attribute__((address_space(3))) void*)(l), 16, 0, 0)

// ---------------------------------------------------------------- mega-preamble
// ranges: [0,1280) W-transpose | [1280,6336) hbuf | [6336,6356) bias
//         [6356,6380) M3 direct (no atomics) | [6380,6693) edge histogram
__global__ __launch_bounds__(256)
void preamble(const float* __restrict__ Wl, const float* __restrict__ Wr,
              const float* __restrict__ outW, bf16_t* __restrict__ WT,
              bf16_t* __restrict__ OWT,
              const float* __restrict__ x, const int* __restrict__ ntypes,
              const float* __restrict__ nte, bf16_t* __restrict__ hbuf,
              const float* __restrict__ bl, const float* __restrict__ br,
              const float* __restrict__ outb, float* __restrict__ biasb,
              const float* __restrict__ ete, const float* __restrict__ We,
              float* __restrict__ M3L,
              const int* __restrict__ dsts, const int* __restrict__ etype,
              int* __restrict__ deg3)
{
    __shared__ float tile[64][65];
    int b = blockIdx.x;
    int tid = threadIdx.x;
    if (b < 1280) {
        int z = b >> 8, rem = b & 255;
        int bx = rem & 15, by = rem >> 4;
        const float* src;
        bf16_t* dstp;
        switch (z) {
            case 0: src = Wl;                       dstp = WT;                        break;
            case 1: src = Wr;                       dstp = WT + (size_t)1024*1024;    break;
            case 2: src = Wl + (size_t)1024*1024;   dstp = WT + (size_t)2*1024*1024;  break;
            case 3: src = Wr + (size_t)1024*1024;   dstp = WT + (size_t)3*1024*1024;  break;
            default: src = outW;                    dstp = OWT;                       break;
        }
        int tx = tid & 15, ty = tid >> 4;      // tx: 4-col group, ty: row (16/pass)
#pragma unroll
        for (int p = 0; p < 4; ++p) {
            int r = ty + p*16;
            f32x4 rv = *(const f32x4*)(src + (size_t)(by*64 + r)*1024 + bx*64 + tx*4);
#pragma unroll
            for (int j = 0; j < 4; ++j) tile[r][tx*4 + j] = rv[j];
        }
        __syncthreads();
        int v = tid & 7, u0 = tid >> 3;        // v: 8-col group of output, u: out row
#pragma unroll
        for (int p = 0; p < 2; ++p) {
            int u = u0 + p*32;
            bf16x8 ov;
#pragma unroll
            for (int j = 0; j < 8; ++j) ov[j] = (bf16_t)tile[v*8 + j][u];
            *(bf16x8*)(dstp + (size_t)(bx*64 + u)*1024 + by*64 + v*8) = ov;
        }
    } else if (b < 6336) {
        size_t idx = ((size_t)(b - 1280)*256 + tid) * 8;
        if (idx >= (size_t)MPAD*1024) return;
        int n = (int)(idx >> 10);
        int c = (int)(idx & 1023);
        bf16x8 outv;
        if (n < NN) {
            const float* xp = x + (size_t)n*1024 + c;
            int t = ntypes[n];
            const float* ep = nte + (size_t)t*1024 + c;
            f32x4 xa = *(const f32x4*)(xp);
            f32x4 xb = *(const f32x4*)(xp + 4);
            f32x4 ea = *(const f32x4*)(ep);
            f32x4 eb = *(const f32x4*)(ep + 4);
#pragma unroll
            for (int j = 0; j < 4; ++j) {
                outv[j]     = (bf16_t)(xa[j] + ea[j]);
                outv[4 + j] = (bf16_t)(xb[j] + eb[j]);
            }
        } else {
#pragma unroll
            for (int j = 0; j < 8; ++j) outv[j] = (bf16_t)0.f;
        }
        *(bf16x8*)(hbuf + idx) = outv;
    } else if (b < 6356) {
        int i = (b - 6336)*256 + tid;
        if (i < 4096) {
            int l = i >> 11, j = i & 2047;
            biasb[i] = (j < 1024) ? bl[l*1024 + j] : br[l*1024 + j - 1024];
        } else if (i < 5120) {
            biasb[i] = outb[i - 4096];
        }
    } else if (b < 6380) {
        // M3 direct: 24 blocks; (l,t) uniform per block -> ete[] is a scalar load
        int idx = b - 6356;
        int l  = idx / 12;
        int rem = idx % 12;
        int t  = rem >> 2;
        int j  = (rem & 3) * 256 + tid;
        const float* WeL = We + (size_t)l*1024*1024 + j;
        const float* ev  = ete + t*1024;
        float a = 0.f;
#pragma unroll 8
        for (int k = 0; k < 1024; ++k)
            a += ev[k] * WeL[(size_t)k*1024];
        M3L[l*3072 + t*1024 + j] = a;
    } else {
        int e = (b - 6380)*256 + tid;
        if (e < EE) atomicAdd(&deg3[dsts[e]*3 + etype[e]], 1);
    }
}

// ---------------------------------------------------------------- CSR scan + fill
__global__ __launch_bounds__(1024)
void scan_csr(const int* __restrict__ deg3, int* __restrict__ rp3, int* __restrict__ cursor3)
{
    __shared__ int tot[1024];
    int t = threadIdx.x;
    int base = t * 30;
    int v[30];
    int run = 0;
#pragma unroll
    for (int j = 0; j < 30; ++j) {
        int i = base + j;
        int d = (i < 3*NN) ? deg3[i] : 0;
        run += d;
        v[j] = run;
    }
    tot[t] = run;
    __syncthreads();
    for (int d = 1; d < 1024; d <<= 1) {
        int xv = (t >= d) ? tot[t - d] : 0;
        __syncthreads();
        tot[t] += xv;
        __syncthreads();
    }
    int ex = (t == 0) ? 0 : tot[t - 1];
#pragma unroll
    for (int j = 0; j < 30; ++j) {
        int i = base + j;
        if (i < 3*NN) {
            int incl = ex + v[j];
            rp3[i + 1] = incl;
            if (i + 1 < 3*NN) cursor3[i + 1] = incl;
        }
    }
    if (t == 0) { rp3[0] = 0; cursor3[0] = 0; }
}

__global__ void fill_csr(const int* __restrict__ srcs, const int* __restrict__ dsts,
                         const int* __restrict__ etype, int* __restrict__ cursor3,
                         int* __restrict__ sorted_src)
{
    int e = blockIdx.x*256 + threadIdx.x;
    if (e < EE) {
        int d = dsts[e];
        int t = etype[e];
        int pos = atomicAdd(&cursor3[d*3 + t], 1);
        sorted_src[pos] = srcs[e];
    }
}

// ---------------------------------------------------------------- GEMM: BK=64 + XOR-swizzled LDS
// (proven m97-structure: 32 KiB LDS, 80 VGPR -> 5 blocks/CU, whole grid co-resident)
template <typename OT>
__global__ __launch_bounds__(256)
void gemm_bt(const bf16_t* __restrict__ A, const bf16_t* __restrict__ BT,
             const float* __restrict__ bias, OT* __restrict__ Cmat,
             int K, int Ntot, int storeM, int mtiles, int ntiles)
{
    __shared__ __align__(16) bf16_t As[128*64];
    __shared__ __align__(16) bf16_t Bs[128*64];
    const int tid  = threadIdx.x;
    const int wave = tid >> 6;
    const int lane = tid & 63;

    const int GROUP_M = 8;
    int pid = blockIdx.x;
    int in_group = GROUP_M * ntiles;
    int gid = pid / in_group;
    int first_m = gid * GROUP_M;
    int gsz = mtiles - first_m; if (gsz > GROUP_M) gsz = GROUP_M;
    int local = pid % in_group;
    const int m0 = (first_m + (local % gsz)) * 128;
    const int n0 = (local / gsz) * 128;

    const int wm = (wave & 1) * 64;
    const int wn = (wave >> 1) * 64;
    const int quad = lane >> 4;
    const int l16  = lane & 15;

    const int srow = lane >> 3;
    const int gcol = ((lane & 7) ^ srow) * 8;

    f32x4 acc[4][4];
    f32x4 zero = {0.f, 0.f, 0.f, 0.f};
#pragma unroll
    for (int i = 0; i < 4; ++i)
#pragma unroll
        for (int j = 0; j < 4; ++j) acc[i][j] = zero;

    const bf16_t* aBase = A  + (size_t)(m0 + wave*8 + srow) * K + gcol;
    const bf16_t* bBase = BT + (size_t)(n0 + wave*8 + srow) * K + gcol;
    bf16_t* asDst = As + wave*512;
    bf16_t* bsDst = Bs + wave*512;

    for (int k0 = 0; k0 < K; k0 += 64) {
#pragma unroll
        for (int j = 0; j < 4; ++j)
            GLOAD_LDS16(aBase + (size_t)(j*32)*K + k0, asDst + j*2048);
#pragma unroll
        for (int j = 0; j < 4; ++j)
            GLOAD_LDS16(bBase + (size_t)(j*32)*K + k0, bsDst + j*2048);
        __syncthreads();
#pragma unroll
        for (int kk = 0; kk < 2; ++kk) {
            bf16x8 af[4], bfr[4];
#pragma unroll
            for (int mi = 0; mi < 4; ++mi) {
                int row = wm + mi*16 + l16;
                int ch  = ((kk*4 + quad) ^ (row & 7)) * 8;
                af[mi] = *(const bf16x8*)(As + row*64 + ch);
            }
#pragma unroll
            for (int ni = 0; ni < 4; ++ni) {
                int row = wn + ni*16 + l16;
                int ch  = ((kk*4 + quad) ^ (row & 7)) * 8;
                bfr[ni] = *(const bf16x8*)(Bs + row*64 + ch);
            }
#pragma unroll
            for (int mi = 0; mi < 4; ++mi)
#pragma unroll
                for (int ni = 0; ni < 4; ++ni)
                    acc[mi][ni] = __builtin_amdgcn_mfma_f32_16x16x32_bf16(af[mi], bfr[ni], acc[mi][ni], 0, 0, 0);
        }
        __syncthreads();
    }

#pragma unroll
    for (int mi = 0; mi < 4; ++mi) {
#pragma unroll
        for (int ni = 0; ni < 4; ++ni) {
            int col = n0 + wn + ni*16 + l16;
            float bv = bias[col];
#pragma unroll
            for (int r = 0; r < 4; ++r) {
                int row = m0 + wm + mi*16 + quad*4 + r;
                if (row < storeM)
                    Cmat[(size_t)row * Ntot + col] = (OT)(acc[mi][ni][r] + bv);
            }
        }
    }
}

// ---------------------------------------------------------------- fused: logits + softmax + aggregate + residual
// v6: type-segmented CSR, 8 ch/lane, 2 nodes/block, no LDS/syncs,
// depth-2 software pipeline on the ssrc->gather chain (named regs, static idx).
__global__ __launch_bounds__(256)
void fused_edge(const int* __restrict__ rp3, const int* __restrict__ ssrc,
                const bf16_t* __restrict__ XLXR,
                const float* __restrict__ M3, const float* __restrict__ attv,
                const float* __restrict__ cbias, bf16_t* __restrict__ hbuf)
{
    int node = blockIdx.x*2 + (threadIdx.x >> 7);
    int q = threadIdx.x & 127;   // 0..127, 8 ch each
    int c8 = q * 8;

    int b   = __builtin_amdgcn_readfirstlane(rp3[3*node]);
    int t1g = __builtin_amdgcn_readfirstlane(rp3[3*node + 1]);
    int t2g = __builtin_amdgcn_readfirstlane(rp3[3*node + 2]);
    int en  = __builtin_amdgcn_readfirstlane(rp3[3*node + 3]);

    bf16x8 xlv = *(const bf16x8*)(XLXR + (size_t)node*2048 + c8);
    bf16x8 xrv = *(const bf16x8*)(XLXR + (size_t)node*2048 + 1024 + c8);
    float xr[8], at[8], q0[8], q1[8], q2[8];
#pragma unroll
    for (int j = 0; j < 8; ++j) xr[j] = (float)xrv[j];
    f32x4 a_lo = *(const f32x4*)(attv + c8);
    f32x4 a_hi = *(const f32x4*)(attv + c8 + 4);
#pragma unroll
    for (int j = 0; j < 4; ++j) { at[j] = a_lo[j]; at[4+j] = a_hi[j]; }
#pragma unroll
    for (int j = 0; j < 8; ++j) {
        q0[j] = xr[j] + M3[c8 + j];
        q1[j] = xr[j] + M3[1024 + c8 + j];
        q2[j] = xr[j] + M3[2048 + c8 + j];
    }

    float acc[8] = {0.f, 0.f, 0.f, 0.f, 0.f, 0.f, 0.f, 0.f};
    float den = 0.f;

    bf16x8 xs_cur, xs_next;
    if (b < en) {
        int s0 = ssrc[b];
        xs_cur = *(const bf16x8*)(XLXR + (size_t)s0*2048 + c8);
    }

    auto compute = [&](const float (&p)[8]) {
        float x[8];
        float part = 0.f;
#pragma unroll
        for (int j = 0; j < 8; ++j) {
            x[j] = (float)xs_cur[j];
            float v = x[j] + p[j];
            v = fmaxf(v, NEGS * v);       // leaky_relu
            part += v * at[j];
        }
        part += __shfl_xor(part, 1);
        part += __shfl_xor(part, 2);
        part += __shfl_xor(part, 4);
        part += __shfl_xor(part, 8);
        part = fminf(fmaxf(part, -60.f), 60.f);
        float pe = __expf(part);
        den += pe;
#pragma unroll
        for (int j = 0; j < 8; ++j) acc[j] += pe * x[j];
    };

    for (int i = b; i < en; ++i) {
        if (i + 1 < en) {
            int sn = ssrc[i + 1];
            xs_next = *(const bf16x8*)(XLXR + (size_t)sn*2048 + c8);
        }
        if (i < t1g)      compute(q0);   // wave-uniform branches (i,t1g,t2g in SGPR)
        else if (i < t2g) compute(q1);
        else              compute(q2);
        xs_cur = xs_next;
    }

    float cnt0 = (float)(t1g - b);
    float cnt1 = (float)(t2g - t1g);
    float cnt2 = (float)(en - t2g);
    float degf = cnt0 + cnt1 + cnt2;
    float inv = 1.f / fmaxf(degf, 1.f);
    float w0 = cnt0 * inv, w1 = cnt1 * inv, w2 = cnt2 * inv;
    float sw = w0 + w1 + w2;              // 1 if deg>0 else 0
    float sx[8];
    float sp = 0.f;
#pragma unroll
    for (int j = 0; j < 8; ++j) {
        sx[j] = (float)xlv[j];
        float u = sx[j] + xr[j]*(1.f - sw) + w0*q0[j] + w1*q1[j] + w2*q2[j];
        u = fmaxf(u, NEGS * u);
        sp += u * at[j];
    }
    sp += __shfl_xor(sp, 1);
    sp += __shfl_xor(sp, 2);
    sp += __shfl_xor(sp, 4);
    sp += __shfl_xor(sp, 8);
    sp = fminf(fmaxf(sp, -60.f), 60.f);
    float ps = __expf(sp);
    den += ps;
#pragma unroll
    for (int j = 0; j < 8; ++j) acc[j] += ps * sx[j];

    float invd = 1.f / den;
    bf16x8 hv = *(const bf16x8*)(hbuf + (size_t)node*1024 + c8);
    bf16x8 outv;
#pragma unroll
    for (int j = 0; j < 8; ++j)
        outv[j] = (bf16_t)((float)hv[j] + fmaxf(acc[j]*invd + cbias[c8 + j], 0.f));
    *(bf16x8*)(hbuf + (size_t)node*1024 + c8) = outv;
}

// ---------------------------------------------------------------- launch
extern "C" void kernel_launch(void* const* d_in, const int* in_sizes, int n_in,
                              void* d_out, int out_size, void* d_ws, size_t ws_size,
                              hipStream_t stream)
{
    (void)in_sizes; (void)n_in; (void)out_size; (void)ws_size;
    const float* x     = (const float*)d_in[0];
    const int*   eidx  = (const int*)d_in[1];
    const int*   etype = (const int*)d_in[2];
    const int*   ntyp  = (const int*)d_in[3];
    const float* nte   = (const float*)d_in[4];
    const float* ete   = (const float*)d_in[5];
    const float* Wl    = (const float*)d_in[6];
    const float* bl    = (const float*)d_in[7];
    const float* Wr    = (const float*)d_in[8];
    const float* br    = (const float*)d_in[9];
    const float* We    = (const float*)d_in[10];
    const float* attw  = (const float*)d_in[11];
    const float* cbias = (const float*)d_in[12];
    const float* outW  = (const float*)d_in[13];
    const float* outb  = (const float*)d_in[14];
    const int* srcs = eidx;
    const int* dsts = eidx + EE;

    char* wsp = (char*)d_ws;
    size_t off = 0;
    auto carve = [&](size_t bytes) -> void* {
        void* pp = wsp + off;
        off += (bytes + 255) & ~(size_t)255;
        return pp;
    };
    bf16_t* hbuf  = (bf16_t*)carve((size_t)MPAD*1024*2);
    bf16_t* XLXR  = (bf16_t*)carve((size_t)MPAD*2048*2);
    bf16_t* WT    = (bf16_t*)carve((size_t)LL*2048*1024*2);
    bf16_t* OWT   = (bf16_t*)carve((size_t)1024*1024*2);
    float*  M3L   = (float*)carve((size_t)LL*3072*4);
    float*  biasb = (float*)carve(5120*4);
    int* deg3    = (int*)carve((size_t)3*NN*4);
    int* rp3     = (int*)carve((size_t)(3*NN+1)*4);
    int* cursor3 = (int*)carve((size_t)3*NN*4);
    int* ssrc    = (int*)carve((size_t)EE*4);

    hipMemsetAsync(deg3, 0, (size_t)3*NN*4, stream);
    preamble<<<6693, 256, 0, stream>>>(Wl, Wr, outW, WT, OWT,
                                       x, ntyp, nte, hbuf,
                                       bl, br, outb, biasb,
                                       ete, We, M3L,
                                       dsts, etype, deg3);
    scan_csr<<<1, 1024, 0, stream>>>(deg3, rp3, cursor3);
    fill_csr<<<(EE + 255)/256, 256, 0, stream>>>(srcs, dsts, etype, cursor3, ssrc);

    for (int l = 0; l < LL; ++l) {
        gemm_bt<bf16_t><<<79*16, 256, 0, stream>>>(hbuf, WT + (size_t)l*2048*1024,
                                                   biasb + l*2048, XLXR,
                                                   1024, 2048, MPAD, 79, 16);
        fused_edge<<<NN/2, 256, 0, stream>>>(rp3, ssrc, XLXR, M3L + l*3072, attw + l*1024,
                                             cbias + l*1024, hbuf);
    }

    gemm_bt<float><<<79*8, 256, 0, stream>>>(hbuf, OWT, biasb + 4096, (float*)d_out,
                                             1024, 1024, NN, 79, 8);
}

// Round 8
// 419.458 us; speedup vs baseline: 1.1362x; 1.1362x over previous
//
#include <hip/hip_runtime.h>
#include <hip/hip_bf16.h>
#include <stdint.h>

typedef __bf16 bf16_t;
typedef bf16_t bf16x8 __attribute__((ext_vector_type(8)));
typedef bf16_t bf16x4 __attribute__((ext_vector_type(4)));
typedef float f32x4 __attribute__((ext_vector_type(4)));

#define NN 10000
#define EE 80000
#define DD 1024
#define LL 2
#define MPAD 10112   /* 79*128 */
#define NEGS 0.2f

#define GLOAD_LDS16(g, l) \
    __builtin_amdgcn_global_load_lds((__attribute__((address_space(1))) void*)(void*)(g), \
                                     (__attribute__((address_space(3))) void*)(l), 16, 0, 0)

// ---------------------------------------------------------------- mega-preamble
// transpose: 64x64 tiles, f32x4 reads, pad-65 LDS (2-way only), bf16x8 writes
__global__ __launch_bounds__(256)
void preamble(const float* __restrict__ Wl, const float* __restrict__ Wr,
              const float* __restrict__ outW, bf16_t* __restrict__ WT,
              bf16_t* __restrict__ OWT,
              const float* __restrict__ x, const int* __restrict__ ntypes,
              const float* __restrict__ nte, bf16_t* __restrict__ hbuf,
              const float* __restrict__ bl, const float* __restrict__ br,
              const float* __restrict__ outb, float* __restrict__ biasb,
              float* __restrict__ M3L, int* __restrict__ deg3)
{
    __shared__ float tile[64][65];
    int b = blockIdx.x;
    int tid = threadIdx.x;
    if (b < 1280) {
        int z = b >> 8, rem = b & 255;
        int bx = rem & 15, by = rem >> 4;
        const float* src;
        bf16_t* dstp;
        switch (z) {
            case 0: src = Wl;                       dstp = WT;                        break;
            case 1: src = Wr;                       dstp = WT + (size_t)1024*1024;    break;
            case 2: src = Wl + (size_t)1024*1024;   dstp = WT + (size_t)2*1024*1024;  break;
            case 3: src = Wr + (size_t)1024*1024;   dstp = WT + (size_t)3*1024*1024;  break;
            default: src = outW;                    dstp = OWT;                       break;
        }
        int tx = tid & 15, ty = tid >> 4;      // tx: 4-col group, ty: row (16/pass)
#pragma unroll
        for (int p = 0; p < 4; ++p) {
            int r = ty + p*16;
            f32x4 rv = *(const f32x4*)(src + (size_t)(by*64 + r)*1024 + bx*64 + tx*4);
#pragma unroll
            for (int j = 0; j < 4; ++j) tile[r][tx*4 + j] = rv[j];
        }
        __syncthreads();
        int v = tid & 7, u0 = tid >> 3;        // v: 8-col group of output, u: out row
#pragma unroll
        for (int p = 0; p < 2; ++p) {
            int u = u0 + p*32;
            bf16x8 ov;
#pragma unroll
            for (int j = 0; j < 8; ++j) ov[j] = (bf16_t)tile[v*8 + j][u];
            *(bf16x8*)(dstp + (size_t)(bx*64 + u)*1024 + by*64 + v*8) = ov;
        }
    } else if (b < 6336) {
        size_t idx = ((size_t)(b - 1280)*256 + tid) * 8;
        if (idx >= (size_t)MPAD*1024) return;
        int n = (int)(idx >> 10);
        int c = (int)(idx & 1023);
        bf16x8 outv;
        if (n < NN) {
            const float* xp = x + (size_t)n*1024 + c;
            int t = ntypes[n];
            const float* ep = nte + (size_t)t*1024 + c;
            f32x4 xa = *(const f32x4*)(xp);
            f32x4 xb = *(const f32x4*)(xp + 4);
            f32x4 ea = *(const f32x4*)(ep);
            f32x4 eb = *(const f32x4*)(ep + 4);
#pragma unroll
            for (int j = 0; j < 4; ++j) {
                outv[j]     = (bf16_t)(xa[j] + ea[j]);
                outv[4 + j] = (bf16_t)(xb[j] + eb[j]);
            }
        } else {
#pragma unroll
            for (int j = 0; j < 8; ++j) outv[j] = (bf16_t)0.f;
        }
        *(bf16x8*)(hbuf + idx) = outv;
    } else if (b < 6356) {
        int i = (b - 6336)*256 + tid;
        if (i < 4096) {
            int l = i >> 11, j = i & 2047;
            biasb[i] = (j < 1024) ? bl[l*1024 + j] : br[l*1024 + j - 1024];
        } else if (i < 5120) {
            biasb[i] = outb[i - 4096];
        }
    } else if (b < 6380) {
        int i = (b - 6356)*256 + tid;
        if (i < LL*3072) M3L[i] = 0.f;
    } else {
        int i = (b - 6380)*256 + tid;
        if (i < 3*NN) deg3[i] = 0;
    }
}

// ---------------------------------------------------------------- aux: M3 (both layers) + edge histogram, one launch
__global__ __launch_bounds__(256)
void aux_k(const float* __restrict__ ete, const float* __restrict__ We,
           float* __restrict__ M3L,
           const int* __restrict__ dsts, const int* __restrict__ etype,
           int* __restrict__ deg3)
{
    int b = blockIdx.x;
    if (b < 512) {
        int l   = b >> 8;
        int bid = b & 255;
        const float* WeL = We + (size_t)l*1024*1024;
        float* M3 = M3L + l*3072;
        int j  = (bid & 3) * 256 + threadIdx.x;
        int k0 = (bid >> 2) * 16;
        float a0 = 0.f, a1 = 0.f, a2 = 0.f;
#pragma unroll
        for (int kk = 0; kk < 16; ++kk) {
            int k = k0 + kk;
            float w = WeL[(size_t)k*1024 + j];
            a0 += ete[k]        * w;
            a1 += ete[1024 + k] * w;
            a2 += ete[2048 + k] * w;
        }
        atomicAdd(&M3[j],        a0);
        atomicAdd(&M3[1024 + j], a1);
        atomicAdd(&M3[2048 + j], a2);
    } else {
        int e = (b - 512)*256 + threadIdx.x;
        if (e < EE) atomicAdd(&deg3[dsts[e]*3 + etype[e]], 1);
    }
}

// ---------------------------------------------------------------- CSR scan + fill
__global__ __launch_bounds__(1024)
void scan_csr(const int* __restrict__ deg3, int* __restrict__ rp3, int* __restrict__ cursor3)
{
    __shared__ int tot[1024];
    int t = threadIdx.x;
    int base = t * 30;
    int v[30];
    int run = 0;
#pragma unroll
    for (int j = 0; j < 30; ++j) {
        int i = base + j;
        int d = (i < 3*NN) ? deg3[i] : 0;
        run += d;
        v[j] = run;
    }
    tot[t] = run;
    __syncthreads();
    for (int d = 1; d < 1024; d <<= 1) {
        int xv = (t >= d) ? tot[t - d] : 0;
        __syncthreads();
        tot[t] += xv;
        __syncthreads();
    }
    int ex = (t == 0) ? 0 : tot[t - 1];
#pragma unroll
    for (int j = 0; j < 30; ++j) {
        int i = base + j;
        if (i < 3*NN) {
            int incl = ex + v[j];
            rp3[i + 1] = incl;
            if (i + 1 < 3*NN) cursor3[i + 1] = incl;
        }
    }
    if (t == 0) { rp3[0] = 0; cursor3[0] = 0; }
}

__global__ void fill_csr(const int* __restrict__ srcs, const int* __restrict__ dsts,
                         const int* __restrict__ etype, int* __restrict__ cursor3,
                         int* __restrict__ sorted_src)
{
    int e = blockIdx.x*256 + threadIdx.x;
    if (e < EE) {
        int d = dsts[e];
        int t = etype[e];
        int pos = atomicAdd(&cursor3[d*3 + t], 1);
        sorted_src[pos] = srcs[e];
    }
}

// ---------------------------------------------------------------- GEMM: BK=64 + XOR-swizzled LDS
// + XCD-bijective block swizzle (grid%8==0 at all call sites): each XCD gets a
// contiguous pid chunk so a GROUP_M cluster's 2MB A-panel stays in its 4MB L2.
template <typename OT>
__global__ __launch_bounds__(256)
void gemm_bt(const bf16_t* __restrict__ A, const bf16_t* __restrict__ BT,
             const float* __restrict__ bias, OT* __restrict__ Cmat,
             int K, int Ntot, int storeM, int mtiles, int ntiles)
{
    __shared__ __align__(16) bf16_t As[128*64];
    __shared__ __align__(16) bf16_t Bs[128*64];
    const int tid  = threadIdx.x;
    const int wave = tid >> 6;
    const int lane = tid & 63;

    const int GROUP_M = 8;
    const int nwg = gridDim.x;
    const int cpx = nwg >> 3;
    const int bidx = blockIdx.x;
    int pid = (bidx & 7) * cpx + (bidx >> 3);   // bijective XCD-chunked remap
    int in_group = GROUP_M * ntiles;
    int gid = pid / in_group;
    int first_m = gid * GROUP_M;
    int gsz = mtiles - first_m; if (gsz > GROUP_M) gsz = GROUP_M;
    int local = pid % in_group;
    const int m0 = (first_m + (local % gsz)) * 128;
    const int n0 = (local / gsz) * 128;

    const int wm = (wave & 1) * 64;
    const int wn = (wave >> 1) * 64;
    const int quad = lane >> 4;
    const int l16  = lane & 15;

    const int srow = lane >> 3;
    const int gcol = ((lane & 7) ^ srow) * 8;

    f32x4 acc[4][4];
    f32x4 zero = {0.f, 0.f, 0.f, 0.f};
#pragma unroll
    for (int i = 0; i < 4; ++i)
#pragma unroll
        for (int j = 0; j < 4; ++j) acc[i][j] = zero;

    const bf16_t* aBase = A  + (size_t)(m0 + wave*8 + srow) * K + gcol;
    const bf16_t* bBase = BT + (size_t)(n0 + wave*8 + srow) * K + gcol;
    bf16_t* asDst = As + wave*512;
    bf16_t* bsDst = Bs + wave*512;

    for (int k0 = 0; k0 < K; k0 += 64) {
#pragma unroll
        for (int j = 0; j < 4; ++j)
            GLOAD_LDS16(aBase + (size_t)(j*32)*K + k0, asDst + j*2048);
#pragma unroll
        for (int j = 0; j < 4; ++j)
            GLOAD_LDS16(bBase + (size_t)(j*32)*K + k0, bsDst + j*2048);
        __syncthreads();
#pragma unroll
        for (int kk = 0; kk < 2; ++kk) {
            bf16x8 af[4], bfr[4];
#pragma unroll
            for (int mi = 0; mi < 4; ++mi) {
                int row = wm + mi*16 + l16;
                int ch  = ((kk*4 + quad) ^ (row & 7)) * 8;
                af[mi] = *(const bf16x8*)(As + row*64 + ch);
            }
#pragma unroll
            for (int ni = 0; ni < 4; ++ni) {
                int row = wn + ni*16 + l16;
                int ch  = ((kk*4 + quad) ^ (row & 7)) * 8;
                bfr[ni] = *(const bf16x8*)(Bs + row*64 + ch);
            }
#pragma unroll
            for (int mi = 0; mi < 4; ++mi)
#pragma unroll
                for (int ni = 0; ni < 4; ++ni)
                    acc[mi][ni] = __builtin_amdgcn_mfma_f32_16x16x32_bf16(af[mi], bfr[ni], acc[mi][ni], 0, 0, 0);
        }
        __syncthreads();
    }

#pragma unroll
    for (int mi = 0; mi < 4; ++mi) {
#pragma unroll
        for (int ni = 0; ni < 4; ++ni) {
            int col = n0 + wn + ni*16 + l16;
            float bv = bias[col];
#pragma unroll
            for (int r = 0; r < 4; ++r) {
                int row = m0 + wm + mi*16 + quad*4 + r;
                if (row < storeM)
                    Cmat[(size_t)row * Ntot + col] = (OT)(acc[mi][ni][r] + bv);
            }
        }
    }
}

// ---------------------------------------------------------------- fused: logits + softmax + aggregate + residual
// v5 (round-6 proven): type-segmented CSR, 8 ch/lane, 128 threads/node, 2 nodes/block.
// NO LDS, NO syncthreads: edge indices are wave-uniform -> scalar-path loads.
__global__ __launch_bounds__(256)
void fused_edge(const int* __restrict__ rp3, const int* __restrict__ ssrc,
                const bf16_t* __restrict__ XLXR,
                const float* __restrict__ M3, const float* __restrict__ attv,
                const float* __restrict__ cbias, bf16_t* __restrict__ hbuf)
{
    int node = blockIdx.x*2 + (threadIdx.x >> 7);
    int q = threadIdx.x & 127;   // 0..127, 8 ch each
    int c8 = q * 8;

    // force wave-uniform (SGPR) CSR bounds -> scalar loop + s_load of ssrc
    int b   = __builtin_amdgcn_readfirstlane(rp3[3*node]);
    int t1g = __builtin_amdgcn_readfirstlane(rp3[3*node + 1]);
    int t2g = __builtin_amdgcn_readfirstlane(rp3[3*node + 2]);
    int en  = __builtin_amdgcn_readfirstlane(rp3[3*node + 3]);

    bf16x8 xlv = *(const bf16x8*)(XLXR + (size_t)node*2048 + c8);
    bf16x8 xrv = *(const bf16x8*)(XLXR + (size_t)node*2048 + 1024 + c8);
    float xr[8], at[8], q0[8], q1[8], q2[8];
#pragma unroll
    for (int j = 0; j < 8; ++j) xr[j] = (float)xrv[j];
    f32x4 a_lo = *(const f32x4*)(attv + c8);
    f32x4 a_hi = *(const f32x4*)(attv + c8 + 4);
#pragma unroll
    for (int j = 0; j < 4; ++j) { at[j] = a_lo[j]; at[4+j] = a_hi[j]; }
#pragma unroll
    for (int j = 0; j < 8; ++j) {
        q0[j] = xr[j] + M3[c8 + j];
        q1[j] = xr[j] + M3[1024 + c8 + j];
        q2[j] = xr[j] + M3[2048 + c8 + j];
    }

    float acc[8] = {0.f, 0.f, 0.f, 0.f, 0.f, 0.f, 0.f, 0.f};
    float den = 0.f;

    auto body = [&](int i, const float (&p)[8]) {
        int s = ssrc[i];             // wave-uniform address
        bf16x8 xs = *(const bf16x8*)(XLXR + (size_t)s*2048 + c8);
        float x[8];
        float part = 0.f;
#pragma unroll
        for (int j = 0; j < 8; ++j) {
            x[j] = (float)xs[j];
            float v = x[j] + p[j];
            v = fmaxf(v, NEGS * v);       // leaky_relu
            part += v * at[j];
        }
        part += __shfl_xor(part, 1);
        part += __shfl_xor(part, 2);
        part += __shfl_xor(part, 4);
        part += __shfl_xor(part, 8);
        part = fminf(fmaxf(part, -60.f), 60.f);
        float pe = __expf(part);
        den += pe;
#pragma unroll
        for (int j = 0; j < 8; ++j) acc[j] += pe * x[j];
    };

#pragma unroll 2
    for (int i = b; i < t1g; ++i)   body(i, q0);
#pragma unroll 2
    for (int i = t1g; i < t2g; ++i) body(i, q1);
#pragma unroll 2
    for (int i = t2g; i < en; ++i)  body(i, q2);

    float cnt0 = (float)(t1g - b);
    float cnt1 = (float)(t2g - t1g);
    float cnt2 = (float)(en - t2g);
    float degf = cnt0 + cnt1 + cnt2;
    float inv = 1.f / fmaxf(degf, 1.f);
    float w0 = cnt0 * inv, w1 = cnt1 * inv, w2 = cnt2 * inv;
    float sw = w0 + w1 + w2;              // 1 if deg>0 else 0
    float sx[8];
    float sp = 0.f;
#pragma unroll
    for (int j = 0; j < 8; ++j) {
        sx[j] = (float)xlv[j];
        float u = sx[j] + xr[j]*(1.f - sw) + w0*q0[j] + w1*q1[j] + w2*q2[j];
        u = fmaxf(u, NEGS * u);
        sp += u * at[j];
    }
    sp += __shfl_xor(sp, 1);
    sp += __shfl_xor(sp, 2);
    sp += __shfl_xor(sp, 4);
    sp += __shfl_xor(sp, 8);
    sp = fminf(fmaxf(sp, -60.f), 60.f);
    float ps = __expf(sp);
    den += ps;
#pragma unroll
    for (int j = 0; j < 8; ++j) acc[j] += ps * sx[j];

    float invd = 1.f / den;
    bf16x8 hv = *(const bf16x8*)(hbuf + (size_t)node*1024 + c8);
    bf16x8 outv;
#pragma unroll
    for (int j = 0; j < 8; ++j)
        outv[j] = (bf16_t)((float)hv[j] + fmaxf(acc[j]*invd + cbias[c8 + j], 0.f));
    *(bf16x8*)(hbuf + (size_t)node*1024 + c8) = outv;
}

// ---------------------------------------------------------------- launch
extern "C" void kernel_launch(void* const* d_in, const int* in_sizes, int n_in,
                              void* d_out, int out_size, void* d_ws, size_t ws_size,
                              hipStream_t stream)
{
    (void)in_sizes; (void)n_in; (void)out_size; (void)ws_size;
    const float* x     = (const float*)d_in[0];
    const int*   eidx  = (const int*)d_in[1];
    const int*   etype = (const int*)d_in[2];
    const int*   ntyp  = (const int*)d_in[3];
    const float* nte   = (const float*)d_in[4];
    const float* ete   = (const float*)d_in[5];
    const float* Wl    = (const float*)d_in[6];
    const float* bl    = (const float*)d_in[7];
    const float* Wr    = (const float*)d_in[8];
    const float* br    = (const float*)d_in[9];
    const float* We    = (const float*)d_in[10];
    const float* attw  = (const float*)d_in[11];
    const float* cbias = (const float*)d_in[12];
    const float* outW  = (const float*)d_in[13];
    const float* outb  = (const float*)d_in[14];
    const int* srcs = eidx;
    const int* dsts = eidx + EE;

    char* wsp = (char*)d_ws;
    size_t off = 0;
    auto carve = [&](size_t bytes) -> void* {
        void* pp = wsp + off;
        off += (bytes + 255) & ~(size_t)255;
        return pp;
    };
    bf16_t* hbuf  = (bf16_t*)carve((size_t)MPAD*1024*2);
    bf16_t* XLXR  = (bf16_t*)carve((size_t)MPAD*2048*2);
    bf16_t* WT    = (bf16_t*)carve((size_t)LL*2048*1024*2);
    bf16_t* OWT   = (bf16_t*)carve((size_t)1024*1024*2);
    float*  M3L   = (float*)carve((size_t)LL*3072*4);
    float*  biasb = (float*)carve(5120*4);
    int* deg3    = (int*)carve((size_t)3*NN*4);
    int* rp3     = (int*)carve((size_t)(3*NN+1)*4);
    int* cursor3 = (int*)carve((size_t)3*NN*4);
    int* ssrc    = (int*)carve((size_t)EE*4);

    preamble<<<6498, 256, 0, stream>>>(Wl, Wr, outW, WT, OWT,
                                       x, ntyp, nte, hbuf,
                                       bl, br, outb, biasb, M3L, deg3);
    aux_k<<<512 + (EE + 255)/256, 256, 0, stream>>>(ete, We, M3L, dsts, etype, deg3);
    scan_csr<<<1, 1024, 0, stream>>>(deg3, rp3, cursor3);
    fill_csr<<<(EE + 255)/256, 256, 0, stream>>>(srcs, dsts, etype, cursor3, ssrc);

    for (int l = 0; l < LL; ++l) {
        gemm_bt<bf16_t><<<79*16, 256, 0, stream>>>(hbuf, WT + (size_t)l*2048*1024,
                                                   biasb + l*2048, XLXR,
                                                   1024, 2048, MPAD, 79, 16);
        fused_edge<<<NN/2, 256, 0, stream>>>(rp3, ssrc, XLXR, M3L + l*3072, attw + l*1024,
                                             cbias + l*1024, hbuf);
    }

    gemm_bt<float><<<79*8, 256, 0, stream>>>(hbuf, OWT, biasb + 4096, (float*)d_out,
                                             1024, 1024, NN, 79, 8);
}

// Round 9
// 409.605 us; speedup vs baseline: 1.1636x; 1.0241x over previous
//
#include <hip/hip_runtime.h>
#include <hip/hip_bf16.h>
#include <stdint.h>

typedef __bf16 bf16_t;
typedef bf16_t bf16x8 __attribute__((ext_vector_type(8)));
typedef bf16_t bf16x4 __attribute__((ext_vector_type(4)));
typedef float f32x4 __attribute__((ext_vector_type(4)));

#define NN 10000
#define EE 80000
#define DD 1024
#define LL 2
#define MPAD 10112   /* 79*128 */
#define NEGS 0.2f
#define GEMM0_GRID 1264   /* 79*16 */
#define FILL_BLKS 313

#define GLOAD_LDS16(g, l) \
    __builtin_amdgcn_global_load_lds((__attribute__((address_space(1))) void*)(void*)(g), \
                                     (__attribute__((address_space(3))) void*)(l), 16, 0, 0)

// ---------------------------------------------------------------- mega-preamble
// ranges: [0,1280) W-transpose | [1280,6336) hbuf | [6336,6356) bias
//         [6356,6868) M3 atomic (512 blk) | [6868,7181) edge histogram (313 blk)
// deg3/M3L zeroed by hipMemsetAsync before this kernel.
__global__ __launch_bounds__(256)
void preamble(const float* __restrict__ Wl, const float* __restrict__ Wr,
              const float* __restrict__ outW, bf16_t* __restrict__ WT,
              bf16_t* __restrict__ OWT,
              const float* __restrict__ x, const int* __restrict__ ntypes,
              const float* __restrict__ nte, bf16_t* __restrict__ hbuf,
              const float* __restrict__ bl, const float* __restrict__ br,
              const float* __restrict__ outb, float* __restrict__ biasb,
              const float* __restrict__ ete, const float* __restrict__ We,
              float* __restrict__ M3L,
              const int* __restrict__ dsts, const int* __restrict__ etype,
              int* __restrict__ deg3)
{
    __shared__ float tile[64][65];
    int b = blockIdx.x;
    int tid = threadIdx.x;
    if (b < 1280) {
        int z = b >> 8, rem = b & 255;
        int bx = rem & 15, by = rem >> 4;
        const float* src;
        bf16_t* dstp;
        switch (z) {
            case 0: src = Wl;                       dstp = WT;                        break;
            case 1: src = Wr;                       dstp = WT + (size_t)1024*1024;    break;
            case 2: src = Wl + (size_t)1024*1024;   dstp = WT + (size_t)2*1024*1024;  break;
            case 3: src = Wr + (size_t)1024*1024;   dstp = WT + (size_t)3*1024*1024;  break;
            default: src = outW;                    dstp = OWT;                       break;
        }
        int tx = tid & 15, ty = tid >> 4;
#pragma unroll
        for (int p = 0; p < 4; ++p) {
            int r = ty + p*16;
            f32x4 rv = *(const f32x4*)(src + (size_t)(by*64 + r)*1024 + bx*64 + tx*4);
#pragma unroll
            for (int j = 0; j < 4; ++j) tile[r][tx*4 + j] = rv[j];
        }
        __syncthreads();
        int v = tid & 7, u0 = tid >> 3;
#pragma unroll
        for (int p = 0; p < 2; ++p) {
            int u = u0 + p*32;
            bf16x8 ov;
#pragma unroll
            for (int j = 0; j < 8; ++j) ov[j] = (bf16_t)tile[v*8 + j][u];
            *(bf16x8*)(dstp + (size_t)(bx*64 + u)*1024 + by*64 + v*8) = ov;
        }
    } else if (b < 6336) {
        size_t idx = ((size_t)(b - 1280)*256 + tid) * 8;
        if (idx >= (size_t)MPAD*1024) return;
        int n = (int)(idx >> 10);
        int c = (int)(idx & 1023);
        bf16x8 outv;
        if (n < NN) {
            const float* xp = x + (size_t)n*1024 + c;
            int t = ntypes[n];
            const float* ep = nte + (size_t)t*1024 + c;
            f32x4 xa = *(const f32x4*)(xp);
            f32x4 xb = *(const f32x4*)(xp + 4);
            f32x4 ea = *(const f32x4*)(ep);
            f32x4 eb = *(const f32x4*)(ep + 4);
#pragma unroll
            for (int j = 0; j < 4; ++j) {
                outv[j]     = (bf16_t)(xa[j] + ea[j]);
                outv[4 + j] = (bf16_t)(xb[j] + eb[j]);
            }
        } else {
#pragma unroll
            for (int j = 0; j < 8; ++j) outv[j] = (bf16_t)0.f;
        }
        *(bf16x8*)(hbuf + idx) = outv;
    } else if (b < 6356) {
        int i = (b - 6336)*256 + tid;
        if (i < 4096) {
            int l = i >> 11, j = i & 2047;
            biasb[i] = (j < 1024) ? bl[l*1024 + j] : br[l*1024 + j - 1024];
        } else if (i < 5120) {
            biasb[i] = outb[i - 4096];
        }
    } else if (b < 6868) {
        // M3 (both layers): parallel-k atomic accumulation (r8 aux pattern, unchanged)
        int idx = b - 6356;
        int l   = idx >> 8;
        int bid = idx & 255;
        const float* WeL = We + (size_t)l*1024*1024;
        float* M3 = M3L + l*3072;
        int j  = (bid & 3) * 256 + tid;
        int k0 = (bid >> 2) * 16;
        float a0 = 0.f, a1 = 0.f, a2 = 0.f;
#pragma unroll
        for (int kk = 0; kk < 16; ++kk) {
            int k = k0 + kk;
            float w = WeL[(size_t)k*1024 + j];
            a0 += ete[k]        * w;
            a1 += ete[1024 + k] * w;
            a2 += ete[2048 + k] * w;
        }
        atomicAdd(&M3[j],        a0);
        atomicAdd(&M3[1024 + j], a1);
        atomicAdd(&M3[2048 + j], a2);
    } else {
        int e = (b - 6868)*256 + tid;
        if (e < EE) atomicAdd(&deg3[dsts[e]*3 + etype[e]], 1);
    }
}

// ---------------------------------------------------------------- CSR scan
__global__ __launch_bounds__(1024)
void scan_csr(const int* __restrict__ deg3, int* __restrict__ rp3, int* __restrict__ cursor3)
{
    __shared__ int tot[1024];
    int t = threadIdx.x;
    int base = t * 30;
    int v[30];
    int run = 0;
#pragma unroll
    for (int j = 0; j < 30; ++j) {
        int i = base + j;
        int d = (i < 3*NN) ? deg3[i] : 0;
        run += d;
        v[j] = run;
    }
    tot[t] = run;
    __syncthreads();
    for (int d = 1; d < 1024; d <<= 1) {
        int xv = (t >= d) ? tot[t - d] : 0;
        __syncthreads();
        tot[t] += xv;
        __syncthreads();
    }
    int ex = (t == 0) ? 0 : tot[t - 1];
#pragma unroll
    for (int j = 0; j < 30; ++j) {
        int i = base + j;
        if (i < 3*NN) {
            int incl = ex + v[j];
            rp3[i + 1] = incl;
            if (i + 1 < 3*NN) cursor3[i + 1] = incl;
        }
    }
    if (t == 0) { rp3[0] = 0; cursor3[0] = 0; }
}

// ---------------------------------------------------------------- GEMM core (m97 structure,
// XOR-swizzled LDS, 32 KiB, 80 VGPR) shared by plain and fused-fill launches
template <typename OT>
__device__ __forceinline__
void gemm_core(const bf16_t* __restrict__ A, const bf16_t* __restrict__ BT,
               const float* __restrict__ bias, OT* __restrict__ Cmat,
               int K, int Ntot, int storeM, int mtiles, int ntiles, int pid)
{
    __shared__ __align__(16) bf16_t As[128*64];
    __shared__ __align__(16) bf16_t Bs[128*64];
    const int tid  = threadIdx.x;
    const int wave = tid >> 6;
    const int lane = tid & 63;

    const int GROUP_M = 8;
    int in_group = GROUP_M * ntiles;
    int gid = pid / in_group;
    int first_m = gid * GROUP_M;
    int gsz = mtiles - first_m; if (gsz > GROUP_M) gsz = GROUP_M;
    int local = pid % in_group;
    const int m0 = (first_m + (local % gsz)) * 128;
    const int n0 = (local / gsz) * 128;

    const int wm = (wave & 1) * 64;
    const int wn = (wave >> 1) * 64;
    const int quad = lane >> 4;
    const int l16  = lane & 15;

    const int srow = lane >> 3;
    const int gcol = ((lane & 7) ^ srow) * 8;

    f32x4 acc[4][4];
    f32x4 zero = {0.f, 0.f, 0.f, 0.f};
#pragma unroll
    for (int i = 0; i < 4; ++i)
#pragma unroll
        for (int j = 0; j < 4; ++j) acc[i][j] = zero;

    const bf16_t* aBase = A  + (size_t)(m0 + wave*8 + srow) * K + gcol;
    const bf16_t* bBase = BT + (size_t)(n0 + wave*8 + srow) * K + gcol;
    bf16_t* asDst = As + wave*512;
    bf16_t* bsDst = Bs + wave*512;

    for (int k0 = 0; k0 < K; k0 += 64) {
#pragma unroll
        for (int j = 0; j < 4; ++j)
            GLOAD_LDS16(aBase + (size_t)(j*32)*K + k0, asDst + j*2048);
#pragma unroll
        for (int j = 0; j < 4; ++j)
            GLOAD_LDS16(bBase + (size_t)(j*32)*K + k0, bsDst + j*2048);
        __syncthreads();
#pragma unroll
        for (int kk = 0; kk < 2; ++kk) {
            bf16x8 af[4], bfr[4];
#pragma unroll
            for (int mi = 0; mi < 4; ++mi) {
                int row = wm + mi*16 + l16;
                int ch  = ((kk*4 + quad) ^ (row & 7)) * 8;
                af[mi] = *(const bf16x8*)(As + row*64 + ch);
            }
#pragma unroll
            for (int ni = 0; ni < 4; ++ni) {
                int row = wn + ni*16 + l16;
                int ch  = ((kk*4 + quad) ^ (row & 7)) * 8;
                bfr[ni] = *(const bf16x8*)(Bs + row*64 + ch);
            }
#pragma unroll
            for (int mi = 0; mi < 4; ++mi)
#pragma unroll
                for (int ni = 0; ni < 4; ++ni)
                    acc[mi][ni] = __builtin_amdgcn_mfma_f32_16x16x32_bf16(af[mi], bfr[ni], acc[mi][ni], 0, 0, 0);
        }
        __syncthreads();
    }

#pragma unroll
    for (int mi = 0; mi < 4; ++mi) {
#pragma unroll
        for (int ni = 0; ni < 4; ++ni) {
            int col = n0 + wn + ni*16 + l16;
            float bv = bias[col];
#pragma unroll
            for (int r = 0; r < 4; ++r) {
                int row = m0 + wm + mi*16 + quad*4 + r;
                if (row < storeM)
                    Cmat[(size_t)row * Ntot + col] = (OT)(acc[mi][ni][r] + bv);
            }
        }
    }
}

template <typename OT>
__global__ __launch_bounds__(256)
void gemm_bt(const bf16_t* __restrict__ A, const bf16_t* __restrict__ BT,
             const float* __restrict__ bias, OT* __restrict__ Cmat,
             int K, int Ntot, int storeM, int mtiles, int ntiles)
{
    const int cpx = gridDim.x >> 3;
    int pid = ((int)blockIdx.x & 7) * cpx + ((int)blockIdx.x >> 3);
    gemm_core<OT>(A, BT, bias, Cmat, K, Ntot, storeM, mtiles, ntiles, pid);
}

// gemm layer-0 + CSR fill fused in one launch (fill hides under the GEMM)
__global__ __launch_bounds__(256)
void gemm0_fill(const bf16_t* __restrict__ A, const bf16_t* __restrict__ BT,
                const float* __restrict__ bias, bf16_t* __restrict__ Cmat,
                const int* __restrict__ srcs, const int* __restrict__ dsts,
                const int* __restrict__ etype, int* __restrict__ cursor3,
                int* __restrict__ ssrc)
{
    if (blockIdx.x >= GEMM0_GRID) {
        int e = ((int)blockIdx.x - GEMM0_GRID)*256 + (int)threadIdx.x;
        if (e < EE) {
            int d = dsts[e];
            int t = etype[e];
            int pos = atomicAdd(&cursor3[d*3 + t], 1);
            ssrc[pos] = srcs[e];
        }
        return;
    }
    int pid = ((int)blockIdx.x & 7) * (GEMM0_GRID >> 3) + ((int)blockIdx.x >> 3);
    gemm_core<bf16_t>(A, BT, bias, Cmat, 1024, 2048, MPAD, 79, 16, pid);
}

// ---------------------------------------------------------------- fused: logits + softmax + aggregate + residual
// (round-6 proven v5): type-segmented CSR, 8 ch/lane, 2 nodes/block, no LDS/syncs.
__global__ __launch_bounds__(256)
void fused_edge(const int* __restrict__ rp3, const int* __restrict__ ssrc,
                const bf16_t* __restrict__ XLXR,
                const float* __restrict__ M3, const float* __restrict__ attv,
                const float* __restrict__ cbias, bf16_t* __restrict__ hbuf)
{
    int node = blockIdx.x*2 + (threadIdx.x >> 7);
    int q = threadIdx.x & 127;
    int c8 = q * 8;

    int b   = __builtin_amdgcn_readfirstlane(rp3[3*node]);
    int t1g = __builtin_amdgcn_readfirstlane(rp3[3*node + 1]);
    int t2g = __builtin_amdgcn_readfirstlane(rp3[3*node + 2]);
    int en  = __builtin_amdgcn_readfirstlane(rp3[3*node + 3]);

    bf16x8 xlv = *(const bf16x8*)(XLXR + (size_t)node*2048 + c8);
    bf16x8 xrv = *(const bf16x8*)(XLXR + (size_t)node*2048 + 1024 + c8);
    float xr[8], at[8], q0[8], q1[8], q2[8];
#pragma unroll
    for (int j = 0; j < 8; ++j) xr[j] = (float)xrv[j];
    f32x4 a_lo = *(const f32x4*)(attv + c8);
    f32x4 a_hi = *(const f32x4*)(attv + c8 + 4);
#pragma unroll
    for (int j = 0; j < 4; ++j) { at[j] = a_lo[j]; at[4+j] = a_hi[j]; }
#pragma unroll
    for (int j = 0; j < 8; ++j) {
        q0[j] = xr[j] + M3[c8 + j];
        q1[j] = xr[j] + M3[1024 + c8 + j];
        q2[j] = xr[j] + M3[2048 + c8 + j];
    }

    float acc[8] = {0.f, 0.f, 0.f, 0.f, 0.f, 0.f, 0.f, 0.f};
    float den = 0.f;

    auto body = [&](int i, const float (&p)[8]) {
        int s = ssrc[i];
        bf16x8 xs = *(const bf16x8*)(XLXR + (size_t)s*2048 + c8);
        float x[8];
        float part = 0.f;
#pragma unroll
        for (int j = 0; j < 8; ++j) {
            x[j] = (float)xs[j];
            float v = x[j] + p[j];
            v = fmaxf(v, NEGS * v);
            part += v * at[j];
        }
        part += __shfl_xor(part, 1);
        part += __shfl_xor(part, 2);
        part += __shfl_xor(part, 4);
        part += __shfl_xor(part, 8);
        part = fminf(fmaxf(part, -60.f), 60.f);
        float pe = __expf(part);
        den += pe;
#pragma unroll
        for (int j = 0; j < 8; ++j) acc[j] += pe * x[j];
    };

#pragma unroll 2
    for (int i = b; i < t1g; ++i)   body(i, q0);
#pragma unroll 2
    for (int i = t1g; i < t2g; ++i) body(i, q1);
#pragma unroll 2
    for (int i = t2g; i < en; ++i)  body(i, q2);

    float cnt0 = (float)(t1g - b);
    float cnt1 = (float)(t2g - t1g);
    float cnt2 = (float)(en - t2g);
    float degf = cnt0 + cnt1 + cnt2;
    float inv = 1.f / fmaxf(degf, 1.f);
    float w0 = cnt0 * inv, w1 = cnt1 * inv, w2 = cnt2 * inv;
    float sw = w0 + w1 + w2;
    float sx[8];
    float sp = 0.f;
#pragma unroll
    for (int j = 0; j < 8; ++j) {
        sx[j] = (float)xlv[j];
        float u = sx[j] + xr[j]*(1.f - sw) + w0*q0[j] + w1*q1[j] + w2*q2[j];
        u = fmaxf(u, NEGS * u);
        sp += u * at[j];
    }
    sp += __shfl_xor(sp, 1);
    sp += __shfl_xor(sp, 2);
    sp += __shfl_xor(sp, 4);
    sp += __shfl_xor(sp, 8);
    sp = fminf(fmaxf(sp, -60.f), 60.f);
    float ps = __expf(sp);
    den += ps;
#pragma unroll
    for (int j = 0; j < 8; ++j) acc[j] += ps * sx[j];

    float invd = 1.f / den;
    bf16x8 hv = *(const bf16x8*)(hbuf + (size_t)node*1024 + c8);
    bf16x8 outv;
#pragma unroll
    for (int j = 0; j < 8; ++j)
        outv[j] = (bf16_t)((float)hv[j] + fmaxf(acc[j]*invd + cbias[c8 + j], 0.f));
    *(bf16x8*)(hbuf + (size_t)node*1024 + c8) = outv;
}

// ---------------------------------------------------------------- launch
extern "C" void kernel_launch(void* const* d_in, const int* in_sizes, int n_in,
                              void* d_out, int out_size, void* d_ws, size_t ws_size,
                              hipStream_t stream)
{
    (void)in_sizes; (void)n_in; (void)out_size; (void)ws_size;
    const float* x     = (const float*)d_in[0];
    const int*   eidx  = (const int*)d_in[1];
    const int*   etype = (const int*)d_in[2];
    const int*   ntyp  = (const int*)d_in[3];
    const float* nte   = (const float*)d_in[4];
    const float* ete   = (const float*)d_in[5];
    const float* Wl    = (const float*)d_in[6];
    const float* bl    = (const float*)d_in[7];
    const float* Wr    = (const float*)d_in[8];
    const float* br    = (const float*)d_in[9];
    const float* We    = (const float*)d_in[10];
    const float* attw  = (const float*)d_in[11];
    const float* cbias = (const float*)d_in[12];
    const float* outW  = (const float*)d_in[13];
    const float* outb  = (const float*)d_in[14];
    const int* srcs = eidx;
    const int* dsts = eidx + EE;

    char* wsp = (char*)d_ws;
    size_t off = 0;
    auto carve = [&](size_t bytes) -> void* {
        void* pp = wsp + off;
        off += (bytes + 255) & ~(size_t)255;
        return pp;
    };
    bf16_t* hbuf  = (bf16_t*)carve((size_t)MPAD*1024*2);
    bf16_t* XLXR  = (bf16_t*)carve((size_t)MPAD*2048*2);
    bf16_t* WT    = (bf16_t*)carve((size_t)LL*2048*1024*2);
    bf16_t* OWT   = (bf16_t*)carve((size_t)1024*1024*2);
    float*  M3L   = (float*)carve((size_t)LL*3072*4);
    float*  biasb = (float*)carve(5120*4);
    int* deg3    = (int*)carve((size_t)3*NN*4);
    int* rp3     = (int*)carve((size_t)(3*NN+1)*4);
    int* cursor3 = (int*)carve((size_t)3*NN*4);
    int* ssrc    = (int*)carve((size_t)EE*4);

    hipMemsetAsync(deg3, 0, (size_t)3*NN*4, stream);
    hipMemsetAsync(M3L, 0, (size_t)LL*3072*4, stream);
    preamble<<<7181, 256, 0, stream>>>(Wl, Wr, outW, WT, OWT,
                                       x, ntyp, nte, hbuf,
                                       bl, br, outb, biasb,
                                       ete, We, M3L,
                                       dsts, etype, deg3);
    scan_csr<<<1, 1024, 0, stream>>>(deg3, rp3, cursor3);

    gemm0_fill<<<GEMM0_GRID + FILL_BLKS, 256, 0, stream>>>(hbuf, WT, biasb, XLXR,
                                                           srcs, dsts, etype, cursor3, ssrc);
    fused_edge<<<NN/2, 256, 0, stream>>>(rp3, ssrc, XLXR, M3L, attw, cbias, hbuf);

    gemm_bt<bf16_t><<<79*16, 256, 0, stream>>>(hbuf, WT + (size_t)2048*1024,
                                               biasb + 2048, XLXR,
                                               1024, 2048, MPAD, 79, 16);
    fused_edge<<<NN/2, 256, 0, stream>>>(rp3, ssrc, XLXR, M3L + 3072, attw + 1024,
                                         cbias + 1024, hbuf);

    gemm_bt<float><<<79*8, 256, 0, stream>>>(hbuf, OWT, biasb + 4096, (float*)d_out,
                                             1024, 1024, NN, 79, 8);
}